// Round 16
// baseline (109.789 us; speedup 1.0000x reference)
//
#include <hip/hip_runtime.h>
#include <hip/hip_bf16.h>

typedef __bf16 bf16;
typedef __bf16 bf16x8 __attribute__((ext_vector_type(8)));
typedef __bf16 bf16x4 __attribute__((ext_vector_type(4)));
typedef float  f32x4  __attribute__((ext_vector_type(4)));

#define B_  4
#define N_  2048
#define D_  256
#define H_  8
#define DH_ 32
#define QKV_ELEMS (B_*H_*N_*DH_)          // 2,097,152 elems = 4 MB bf16 each

#define QSC    (0.17677669529663687f * 1.4426950408889634f)
#define NBIAS  (-17.312340490667562f)

#if __has_builtin(__builtin_amdgcn_exp2f)
__device__ inline float exp2_hw(float x) { return __builtin_amdgcn_exp2f(x); }
#else
__device__ inline float exp2_hw(float x) {
    float r; asm volatile("v_exp_f32 %0, %1" : "=v"(r) : "v"(x)); return r;
}
#endif

// Async global->LDS DMA, 16 B/lane. LDS base is wave-uniform; HW adds lane*16.
__device__ inline void gload_lds16(const bf16* g, bf16* l) {
    __builtin_amdgcn_global_load_lds(
        (const __attribute__((address_space(1))) void*)g,
        (__attribute__((address_space(3))) void*)l, 16, 0, 0);
}

// s_waitcnt simm16: vm[3:0] | exp(7)<<4 | lgkm(15)<<8  (lgkm/exp left open)
#define WAITCNT_VM0 0x0F70
#define WAITCNT_VM4 0x0F74

__device__ inline bf16x8 ldcvt8(const float* __restrict__ p) {
    f32x4 a = *(const f32x4*)p;
    f32x4 b = *(const f32x4*)(p + 4);
    bf16x8 r;
    r[0] = (bf16)a[0]; r[1] = (bf16)a[1]; r[2] = (bf16)a[2]; r[3] = (bf16)a[3];
    r[4] = (bf16)b[0]; r[5] = (bf16)b[1]; r[6] = (bf16)b[2]; r[7] = (bf16)b[3];
    return r;
}

// ---------------------------------------------------------------------------
// Kernel A: QKV projection (unchanged; ~8 us).
// ---------------------------------------------------------------------------
__global__ __launch_bounds__(256, 4) void qkv_proj_kernel(
    const float* __restrict__ x,
    const float* __restrict__ Wq, const float* __restrict__ bq,
    const float* __restrict__ Wk, const float* __restrict__ bk,
    const float* __restrict__ Wv, const float* __restrict__ bv,
    bf16* __restrict__ Qg, bf16* __restrict__ Kg, bf16* __restrict__ Vg)
{
    const int bh = blockIdx.x & 31, nt = blockIdx.x >> 5;
    const int h  = bh & (H_-1),    b  = bh >> 3;
    const int wave = threadIdx.x >> 6, lane = threadIdx.x & 63;
    const int l16 = lane & 15, q4 = lane >> 4;
    const int n0 = nt*64 + wave*16;

    bf16x8 wqf[2], wkf[2], wvf[2];
    f32x4  bq4[2], bk4[2];
    float  bvs[2];
    #pragma unroll
    for (int half = 0; half < 2; ++half) {
        wqf[half] = ldcvt8(Wq + (h*DH_ + half*16 + l16)*DH_ + q4*8);
        wkf[half] = ldcvt8(Wk + (h*DH_ + half*16 + l16)*DH_ + q4*8);
        wvf[half] = ldcvt8(Wv + (h*DH_ + half*16 + l16)*DH_ + q4*8);
        bq4[half] = *(const f32x4*)(bq + h*DH_ + half*16 + q4*4);
        bk4[half] = *(const f32x4*)(bk + h*DH_ + half*16 + q4*4);
        bvs[half] = bv[h*DH_ + half*16 + l16];
    }

    bf16x8 xf = ldcvt8(x + ((size_t)(b*N_ + n0 + l16))*D_ + h*DH_ + q4*8);
    const f32x4 z = {0.f,0.f,0.f,0.f};

    #pragma unroll
    for (int half = 0; half < 2; ++half) {
        f32x4 dq = __builtin_amdgcn_mfma_f32_16x16x32_bf16(wqf[half], xf, z, 0, 0, 0);
        f32x4 dk = __builtin_amdgcn_mfma_f32_16x16x32_bf16(wkf[half], xf, z, 0, 0, 0);
        f32x4 dv = __builtin_amdgcn_mfma_f32_16x16x32_bf16(xf, wvf[half], z, 0, 0, 0);
        bf16x4 pq, pk, pv;
        #pragma unroll
        for (int r = 0; r < 4; ++r) {
            pq[r] = (bf16)((dq[r] + bq4[half][r]) * QSC);
            pk[r] = (bf16)(dk[r] + bk4[half][r]);
            pv[r] = (bf16)(dv[r] + bvs[half]);
        }
        const size_t row = ((size_t)bh*N_ + n0 + l16)*DH_ + half*16 + q4*4;
        *(bf16x4*)(Qg + row) = pq;
        *(bf16x4*)(Kg + row) = pk;
        const int e = half*16 + l16;
        const size_t idx = ((size_t)bh << 16) + ((size_t)(n0 >> 5) << 10)
                         + (e << 5) + (q4 << 3) + (((n0 >> 4) & 1) << 2);
        *(bf16x4*)(Vg + idx) = pv;
    }
}

// ---------------------------------------------------------------------------
// Kernel B: flash attention, barrier-free + EXPLICIT 2-STAGE INTRA-WAVE
// PIPELINE. Block = (b,h,128-row q-tile), 4 waves x 32 q-rows; grid 512,
// bh-minor. 32-key tiles (64 total), wave-private triple-buffered LDS
// (4 KB/tile: 2 KB K + 2 KB V; 12 KB/wave, 48 KB/block).
// Steady-state iteration i:
//   read V(i) frags           (tile i arrived last iter)
//   s_waitcnt vmcnt(0)        (tile i+1 arrived; issued a full iter ago)
//   read kf(i+1); DMA(i+2) -> buf (i+2)%3  (4 ops back in flight)
//   S(i+1) MFMAs              <- executes UNDER the exp of tile i
//   exp/pack/PV/rowsum on tile i from st computed LAST iteration
// This is the first variant where an S-MFMA's dependent exp is separated by
// a full tile of independent work. Waves staggered (key-order invariant).
// ---------------------------------------------------------------------------
__global__ __launch_bounds__(256, 2) void attn_kernel(
    const bf16* __restrict__ Qg, const bf16* __restrict__ Kg,
    const bf16* __restrict__ Vg, float* __restrict__ out)
{
    const int bh = blockIdx.x & 31;          // bh-minor: XCD-local K/V
    const int qt = blockIdx.x >> 5;
    const int h  = bh & (H_-1), b = bh >> 3;
    const int lane = threadIdx.x & 63;
    const int wave = threadIdx.x >> 6;
    const int l16 = lane & 15, q4 = lane >> 4;

    // per-wave, per-buffer: [0..1023]=K (32 keys x 32 dh), [1024..2047]=V
    __shared__ bf16 L[4][3][2048];           // 48 KB

    const bf16* Kb = Kg + (size_t)bh*N_*DH_;
    const bf16* Vb = Vg + ((size_t)bh << 16);
    const int qrow0 = qt*128 + wave*32;

    bf16x8 qb0 = *(const bf16x8*)(Qg + ((size_t)bh*N_ + qrow0 + l16)*DH_ + q4*8);
    bf16x8 qb1 = *(const bf16x8*)(Qg + ((size_t)bh*N_ + qrow0 + 16 + l16)*DH_ + q4*8);

    bf16x8 ones;
    #pragma unroll
    for (int j = 0; j < 8; ++j) ones[j] = (bf16)1.0f;

    f32x4 ot[2][2];                          // [dh-half][q-half]
    ot[0][0] = (f32x4){0,0,0,0}; ot[0][1] = (f32x4){0,0,0,0};
    ot[1][0] = (f32x4){0,0,0,0}; ot[1][1] = (f32x4){0,0,0,0};
    f32x4 osum0 = {0,0,0,0}, osum1 = {0,0,0,0};
    const f32x4 zb = {NBIAS, NBIAS, NBIAS, NBIAS};

    // per-wave stagger over the 64 32-key tiles (softmax is order-invariant)
    const int start = (((qt*5 + bh)*4 + wave)*9) & 63;
    bf16* Lw = &L[wave][0][0];

    // ---- prologue: DMA tiles start, start+1 into bufs 0,1 (4 ops each)
    #pragma unroll
    for (int d = 0; d < 2; ++d) {
        const int t = (start + d) & 63;
        const bf16* gk = Kb + (size_t)t*1024;
        const bf16* gv = Vb + (size_t)t*1024;
        gload_lds16(gk + lane*8,       Lw + d*2048);
        gload_lds16(gk + 512 + lane*8, Lw + d*2048 + 512);
        gload_lds16(gv + lane*8,       Lw + d*2048 + 1024);
        gload_lds16(gv + 512 + lane*8, Lw + d*2048 + 1536);
    }

    // ---- wait tile 0 (4 newest = tile 1 stay outstanding), compute S(0)
    __builtin_amdgcn_s_waitcnt(WAITCNT_VM4);
    f32x4 stC[2][2];                         // [key-chunk][q-half], tile i
    #pragma unroll
    for (int kc = 0; kc < 2; ++kc) {
        bf16x8 kf = *(const bf16x8*)(Lw + (kc*16 + l16)*DH_ + q4*8);
        stC[kc][0] = __builtin_amdgcn_mfma_f32_16x16x32_bf16(kf, qb0, zb, 0, 0, 0);
        stC[kc][1] = __builtin_amdgcn_mfma_f32_16x16x32_bf16(kf, qb1, zb, 0, 0, 0);
    }

    for (int i = 0; i < 64; ++i) {
        const int bV = i % 3;                // tile i buffer
        const int bK = (i + 1) % 3;          // tile i+1 buffer
        const int bD = (i + 2) % 3;          // DMA target

        // ---- V(i) fragments (tile i fully arrived)
        bf16x8 v0 = *(const bf16x8*)(Lw + bV*2048 + 1024 + l16*DH_ + q4*8);
        bf16x8 v1 = *(const bf16x8*)(Lw + bV*2048 + 1024 + (16 + l16)*DH_ + q4*8);

        f32x4 stN[2][2];
        if (i < 63) {
            // ---- tile i+1 arrived (its 4 DMAs were issued a full iter ago)
            __builtin_amdgcn_s_waitcnt(WAITCNT_VM0);
            bf16x8 kfa = *(const bf16x8*)(Lw + bK*2048 + l16*DH_ + q4*8);
            bf16x8 kfb = *(const bf16x8*)(Lw + bK*2048 + (16 + l16)*DH_ + q4*8);

            // ---- refill the pipe: DMA tile i+2
            if (i < 62) {
                const int t = (start + i + 2) & 63;
                const bf16* gk = Kb + (size_t)t*1024;
                const bf16* gv = Vb + (size_t)t*1024;
                gload_lds16(gk + lane*8,       Lw + bD*2048);
                gload_lds16(gk + 512 + lane*8, Lw + bD*2048 + 512);
                gload_lds16(gv + lane*8,       Lw + bD*2048 + 1024);
                gload_lds16(gv + 512 + lane*8, Lw + bD*2048 + 1536);
            }

            // ---- S(i+1): runs under tile i's exp stream below
            stN[0][0] = __builtin_amdgcn_mfma_f32_16x16x32_bf16(kfa, qb0, zb, 0, 0, 0);
            stN[0][1] = __builtin_amdgcn_mfma_f32_16x16x32_bf16(kfa, qb1, zb, 0, 0, 0);
            stN[1][0] = __builtin_amdgcn_mfma_f32_16x16x32_bf16(kfb, qb0, zb, 0, 0, 0);
            stN[1][1] = __builtin_amdgcn_mfma_f32_16x16x32_bf16(kfb, qb1, zb, 0, 0, 0);
        }

        // ---- tile i: exp -> PV B-operands -> PV + rowsum MFMAs
        bf16x8 pb0, pb1;
        #pragma unroll
        for (int kc = 0; kc < 2; ++kc)
            #pragma unroll
            for (int r = 0; r < 4; ++r) {
                pb0[kc*4 + r] = (bf16)exp2_hw(stC[kc][0][r]);
                pb1[kc*4 + r] = (bf16)exp2_hw(stC[kc][1][r]);
            }
        ot[0][0] = __builtin_amdgcn_mfma_f32_16x16x32_bf16(v0, pb0, ot[0][0], 0, 0, 0);
        ot[1][0] = __builtin_amdgcn_mfma_f32_16x16x32_bf16(v1, pb0, ot[1][0], 0, 0, 0);
        ot[0][1] = __builtin_amdgcn_mfma_f32_16x16x32_bf16(v0, pb1, ot[0][1], 0, 0, 0);
        ot[1][1] = __builtin_amdgcn_mfma_f32_16x16x32_bf16(v1, pb1, ot[1][1], 0, 0, 0);
        osum0 = __builtin_amdgcn_mfma_f32_16x16x32_bf16(ones, pb0, osum0, 0, 0, 0);
        osum1 = __builtin_amdgcn_mfma_f32_16x16x32_bf16(ones, pb1, osum1, 0, 0, 0);

        #pragma unroll
        for (int kc = 0; kc < 2; ++kc) {
            stC[kc][0] = stN[kc][0];
            stC[kc][1] = stN[kc][1];
        }
    }

    // ---- every lane holds the full 2048-key rowsum for its q = l16
    const float inv0 = 1.0f / osum0[0], inv1 = 1.0f / osum1[0];

    #pragma unroll
    for (int qh = 0; qh < 2; ++qh) {
        const float inv = qh ? inv1 : inv0;
        #pragma unroll
        for (int dhh = 0; dhh < 2; ++dhh) {
            f32x4 w;
            #pragma unroll
            for (int r = 0; r < 4; ++r) w[r] = ot[dhh][qh][r] * inv;
            *(f32x4*)(out + ((size_t)b*N_ + qrow0 + qh*16 + l16)*D_
                          + h*DH_ + dhh*16 + q4*4) = w;
        }
    }
}

// ---------------------------------------------------------------------------
extern "C" void kernel_launch(void* const* d_in, const int* in_sizes, int n_in,
                              void* d_out, int out_size, void* d_ws, size_t ws_size,
                              hipStream_t stream)
{
    const float* x  = (const float*)d_in[0];
    const float* Wq = (const float*)d_in[1];
    const float* bq = (const float*)d_in[2];
    const float* Wk = (const float*)d_in[3];
    const float* bk = (const float*)d_in[4];
    const float* Wv = (const float*)d_in[5];
    const float* bv = (const float*)d_in[6];
    float* out = (float*)d_out;

    bf16* Qg = (bf16*)d_ws;
    bf16* Kg = Qg + QKV_ELEMS;
    bf16* Vg = Kg + QKV_ELEMS;

    qkv_proj_kernel<<<dim3(B_*H_*32), dim3(256), 0, stream>>>(
        x, Wq, bq, Wk, bk, Wv, bv, Qg, Kg, Vg);
    attn_kernel<<<dim3(B_*H_*(N_/128)), dim3(256), 0, stream>>>(Qg, Kg, Vg, out);
}

// Round 17
// 103.601 us; speedup vs baseline: 1.0597x; 1.0597x over previous
//
#include <hip/hip_runtime.h>
#include <hip/hip_bf16.h>

typedef __bf16 bf16;
typedef __bf16 bf16x8 __attribute__((ext_vector_type(8)));
typedef __bf16 bf16x4 __attribute__((ext_vector_type(4)));
typedef float  f32x4  __attribute__((ext_vector_type(4)));

#define B_  4
#define N_  2048
#define D_  256
#define H_  8
#define DH_ 32
#define QKV_ELEMS (B_*H_*N_*DH_)          // 2,097,152 elems = 4 MB bf16 each

#define QSC    (0.17677669529663687f * 1.4426950408889634f)
#define NBIAS  (-17.312340490667562f)

#if __has_builtin(__builtin_amdgcn_exp2f)
__device__ inline float exp2_hw(float x) { return __builtin_amdgcn_exp2f(x); }
#else
__device__ inline float exp2_hw(float x) {
    float r; asm volatile("v_exp_f32 %0, %1" : "=v"(r) : "v"(x)); return r;
}
#endif

__device__ inline void gload_lds16(const bf16* g, bf16* l) {
    __builtin_amdgcn_global_load_lds(
        (const __attribute__((address_space(1))) void*)g,
        (__attribute__((address_space(3))) void*)l, 16, 0, 0);
}

__device__ inline bf16x8 ldcvt8(const float* __restrict__ p) {
    f32x4 a = *(const f32x4*)p;
    f32x4 b = *(const f32x4*)(p + 4);
    bf16x8 r;
    r[0] = (bf16)a[0]; r[1] = (bf16)a[1]; r[2] = (bf16)a[2]; r[3] = (bf16)a[3];
    r[4] = (bf16)b[0]; r[5] = (bf16)b[1]; r[6] = (bf16)b[2]; r[7] = (bf16)b[3];
    return r;
}

// ---------------------------------------------------------------------------
// Kernel A: QKV projection (fp32 -> bf16 workspace), vectorized stores.
// Grid 1024, bh-minor (XCD-local writes). ~8 us (BW floor 3.2).
// ---------------------------------------------------------------------------
__global__ __launch_bounds__(256, 4) void qkv_proj_kernel(
    const float* __restrict__ x,
    const float* __restrict__ Wq, const float* __restrict__ bq,
    const float* __restrict__ Wk, const float* __restrict__ bk,
    const float* __restrict__ Wv, const float* __restrict__ bv,
    bf16* __restrict__ Qg, bf16* __restrict__ Kg, bf16* __restrict__ Vg)
{
    const int bh = blockIdx.x & 31, nt = blockIdx.x >> 5;
    const int h  = bh & (H_-1),    b  = bh >> 3;
    const int wave = threadIdx.x >> 6, lane = threadIdx.x & 63;
    const int l16 = lane & 15, q4 = lane >> 4;
    const int n0 = nt*64 + wave*16;

    bf16x8 wqf[2], wkf[2], wvf[2];
    f32x4  bq4[2], bk4[2];
    float  bvs[2];
    #pragma unroll
    for (int half = 0; half < 2; ++half) {
        wqf[half] = ldcvt8(Wq + (h*DH_ + half*16 + l16)*DH_ + q4*8);
        wkf[half] = ldcvt8(Wk + (h*DH_ + half*16 + l16)*DH_ + q4*8);
        wvf[half] = ldcvt8(Wv + (h*DH_ + half*16 + l16)*DH_ + q4*8);
        bq4[half] = *(const f32x4*)(bq + h*DH_ + half*16 + q4*4);
        bk4[half] = *(const f32x4*)(bk + h*DH_ + half*16 + q4*4);
        bvs[half] = bv[h*DH_ + half*16 + l16];
    }

    bf16x8 xf = ldcvt8(x + ((size_t)(b*N_ + n0 + l16))*D_ + h*DH_ + q4*8);
    const f32x4 z = {0.f,0.f,0.f,0.f};

    #pragma unroll
    for (int half = 0; half < 2; ++half) {
        f32x4 dq = __builtin_amdgcn_mfma_f32_16x16x32_bf16(wqf[half], xf, z, 0, 0, 0);
        f32x4 dk = __builtin_amdgcn_mfma_f32_16x16x32_bf16(wkf[half], xf, z, 0, 0, 0);
        f32x4 dv = __builtin_amdgcn_mfma_f32_16x16x32_bf16(xf, wvf[half], z, 0, 0, 0);
        bf16x4 pq, pk, pv;
        #pragma unroll
        for (int r = 0; r < 4; ++r) {
            pq[r] = (bf16)((dq[r] + bq4[half][r]) * QSC);
            pk[r] = (bf16)(dk[r] + bk4[half][r]);
            pv[r] = (bf16)(dv[r] + bvs[half]);
        }
        const size_t row = ((size_t)bh*N_ + n0 + l16)*DH_ + half*16 + q4*4;
        *(bf16x4*)(Qg + row) = pq;
        *(bf16x4*)(Kg + row) = pk;
        const int e = half*16 + l16;
        const size_t idx = ((size_t)bh << 16) + ((size_t)(n0 >> 5) << 10)
                         + (e << 5) + (q4 << 3) + (((n0 >> 4) & 1) << 2);
        *(bf16x4*)(Vg + idx) = pv;
    }
}

// ---------------------------------------------------------------------------
// Kernel B: flash attention — session-best configuration (r14, 102.4 us).
// Block = (b,h,128-row q-tile), 4 waves x 32 q-rows; grid 512, bh-minor.
// Inter-block phase stagger on the key walk (softmax is key-order invariant)
// de-convoys co-resident blocks (+4 us, the only scheduling lever that
// measurably helped). 2-tile barrier period, 4 LDS buffers, global_load_lds
// staging; rowsums on the matrix pipe (all-ones A-frag).
// Structural note: 7 scheduling variants (TLP 2-8 waves/SIMD, barrier-free,
// wave-private pipelines, explicit 2-stage ILP) all land within +-6% — the
// remaining ~3x vs the ~13 us compute floor is fine-grained instruction
// scheduling not expressible at HIP source level (hipBLASLt hand-asm
// territory per learn_hip s02/s10v2).
// ---------------------------------------------------------------------------
__global__ __launch_bounds__(256, 2) void attn_kernel(
    const bf16* __restrict__ Qg, const bf16* __restrict__ Kg,
    const bf16* __restrict__ Vg, float* __restrict__ out)
{
    const int bh = blockIdx.x & 31;          // bh-minor: XCD-local K/V
    const int qt = blockIdx.x >> 5;
    const int h  = bh & (H_-1), b = bh >> 3;
    const int lane = threadIdx.x & 63;
    const int wave = threadIdx.x >> 6;
    const int l16 = lane & 15, q4 = lane >> 4;

    __shared__ bf16 Kl[4][128*DH_];          // 4 x 8 KB
    __shared__ bf16 Vl[4][128*DH_];          // 4 x 8 KB (tile-linear Vg image)

    const bf16* Kb = Kg + (size_t)bh*N_*DH_;
    const bf16* Vb = Vg + ((size_t)bh << 16);
    const int qrow0 = qt*128 + wave*32;
    const int kt0 = ((qt*5 + bh) & 7)*2;     // phase stagger (even tile start)

    bf16x8 qb0 = *(const bf16x8*)(Qg + ((size_t)bh*N_ + qrow0 + l16)*DH_ + q4*8);
    bf16x8 qb1 = *(const bf16x8*)(Qg + ((size_t)bh*N_ + qrow0 + 16 + l16)*DH_ + q4*8);

    bf16x8 ones;
    #pragma unroll
    for (int j = 0; j < 8; ++j) ones[j] = (bf16)1.0f;

    f32x4 ot[2][2];                          // [dh-half][q-half]
    ot[0][0] = (f32x4){0,0,0,0}; ot[0][1] = (f32x4){0,0,0,0};
    ot[1][0] = (f32x4){0,0,0,0}; ot[1][1] = (f32x4){0,0,0,0};
    f32x4 osum0 = {0,0,0,0}, osum1 = {0,0,0,0};
    const f32x4 zb = {NBIAS, NBIAS, NBIAS, NBIAS};

    const int seg = wave*1024 + lane*8;      // per-wave DMA segment

    // ---- prologue: DMA tiles kt0, kt0+1
    #pragma unroll
    for (int d = 0; d < 2; ++d) {
        const int t = (kt0 + d) & 15;
        const bf16* gk = Kb + (size_t)t*4096 + seg;
        const bf16* gv = Vb + (size_t)t*4096 + seg;
        gload_lds16(gk,       &Kl[d][wave*1024]);
        gload_lds16(gk + 512, &Kl[d][wave*1024 + 512]);
        gload_lds16(gv,       &Vl[d][wave*1024]);
        gload_lds16(gv + 512, &Vl[d][wave*1024 + 512]);
    }
    __syncthreads();

    for (int p = 0; p < 8; ++p) {
        // ---- issue next period's DMA (tiles 2p+2, 2p+3 relative)
        #pragma unroll
        for (int d = 2; d < 4; ++d) {
            const int t  = (kt0 + 2*p + d) & 15;
            const int bf = (2*p + d) & 3;
            const bf16* gk = Kb + (size_t)t*4096 + seg;
            const bf16* gv = Vb + (size_t)t*4096 + seg;
            gload_lds16(gk,       &Kl[bf][wave*1024]);
            gload_lds16(gk + 512, &Kl[bf][wave*1024 + 512]);
            gload_lds16(gv,       &Vl[bf][wave*1024]);
            gload_lds16(gv + 512, &Vl[bf][wave*1024 + 512]);
        }

        // ---- compute tiles 2p, 2p+1
        #pragma unroll
        for (int d = 0; d < 2; ++d) {
            const int bf = (2*p + d) & 3;
            f32x4 st[8][2];
            #pragma unroll
            for (int kc = 0; kc < 8; ++kc) {
                bf16x8 kf = *(const bf16x8*)(&Kl[bf][(kc*16 + l16)*DH_ + q4*8]);
                st[kc][0] = __builtin_amdgcn_mfma_f32_16x16x32_bf16(kf, qb0, zb, 0, 0, 0);
                st[kc][1] = __builtin_amdgcn_mfma_f32_16x16x32_bf16(kf, qb1, zb, 0, 0, 0);
            }
            #pragma unroll
            for (int kk = 0; kk < 4; ++kk) {
                bf16x8 pb0, pb1;
                #pragma unroll
                for (int hf = 0; hf < 2; ++hf)
                    #pragma unroll
                    for (int r = 0; r < 4; ++r) {
                        pb0[hf*4 + r] = (bf16)exp2_hw(st[kk*2 + hf][0][r]);
                        pb1[hf*4 + r] = (bf16)exp2_hw(st[kk*2 + hf][1][r]);
                    }
                bf16x8 v0 = *(const bf16x8*)(&Vl[bf][kk*1024 + l16*DH_ + q4*8]);
                bf16x8 v1 = *(const bf16x8*)(&Vl[bf][kk*1024 + (16 + l16)*DH_ + q4*8]);
                ot[0][0] = __builtin_amdgcn_mfma_f32_16x16x32_bf16(v0, pb0, ot[0][0], 0, 0, 0);
                ot[1][0] = __builtin_amdgcn_mfma_f32_16x16x32_bf16(v1, pb0, ot[1][0], 0, 0, 0);
                ot[0][1] = __builtin_amdgcn_mfma_f32_16x16x32_bf16(v0, pb1, ot[0][1], 0, 0, 0);
                ot[1][1] = __builtin_amdgcn_mfma_f32_16x16x32_bf16(v1, pb1, ot[1][1], 0, 0, 0);
                osum0 = __builtin_amdgcn_mfma_f32_16x16x32_bf16(ones, pb0, osum0, 0, 0, 0);
                osum1 = __builtin_amdgcn_mfma_f32_16x16x32_bf16(ones, pb1, osum1, 0, 0, 0);
            }
        }

        __syncthreads();   // buffer handoff; drain covered by 2 bodies
    }

    // ---- every lane already holds the full 2048-key rowsum for its q = l16
    const float inv0 = 1.0f / osum0[0], inv1 = 1.0f / osum1[0];

    #pragma unroll
    for (int qh = 0; qh < 2; ++qh) {
        const float inv = qh ? inv1 : inv0;
        #pragma unroll
        for (int dhh = 0; dhh < 2; ++dhh) {
            f32x4 w;
            #pragma unroll
            for (int r = 0; r < 4; ++r) w[r] = ot[dhh][qh][r] * inv;
            *(f32x4*)(out + ((size_t)b*N_ + qrow0 + qh*16 + l16)*D_
                          + h*DH_ + dhh*16 + q4*4) = w;
        }
    }
}

// ---------------------------------------------------------------------------
extern "C" void kernel_launch(void* const* d_in, const int* in_sizes, int n_in,
                              void* d_out, int out_size, void* d_ws, size_t ws_size,
                              hipStream_t stream)
{
    const float* x  = (const float*)d_in[0];
    const float* Wq = (const float*)d_in[1];
    const float* bq = (const float*)d_in[2];
    const float* Wk = (const float*)d_in[3];
    const float* bk = (const float*)d_in[4];
    const float* Wv = (const float*)d_in[5];
    const float* bv = (const float*)d_in[6];
    float* out = (float*)d_out;

    bf16* Qg = (bf16*)d_ws;
    bf16* Kg = Qg + QKV_ELEMS;
    bf16* Vg = Kg + QKV_ELEMS;

    qkv_proj_kernel<<<dim3(B_*H_*32), dim3(256), 0, stream>>>(
        x, Wq, bq, Wk, bk, Wv, bv, Qg, Kg, Vg);
    attn_kernel<<<dim3(B_*H_*(N_/128)), dim3(256), 0, stream>>>(Qg, Kg, Vg, out);
}